// Round 22
// baseline (230.583 us; speedup 1.0000x reference)
//
#include <hip/hip_runtime.h>
#include <hip/hip_bf16.h>
#include <math.h>

#define B_ 4
#define N_ 1370
#define C_ 1024
#define H_ 16
#define DH_ 64
#define HID_ 4096
#define M_ (B_*N_)      // 5480
#define MPAD 5504       // 43*128 = 86*64
#define NKV 1408        // 11*128 padded kv

typedef short v4s __attribute__((ext_vector_type(4)));
typedef float v16f __attribute__((ext_vector_type(16)));
typedef int v4i __attribute__((ext_vector_type(4)));
typedef int v8i __attribute__((ext_vector_type(8)));

__device__ __forceinline__ char f2fp8(float x) {
  int pk = __builtin_amdgcn_cvt_pk_fp8_f32(x, x, 0, false);
  return (char)(pk & 0xff);
}
__device__ __forceinline__ short f2bf(float x) {
  union { float f; unsigned u; } a; a.f = x;
  unsigned r = (a.u + 0x7fffu + ((a.u >> 16) & 1u)) >> 16;
  return (short)r;
}
__device__ __forceinline__ float bf2f(short s) {
  union { unsigned u; float f; } a; a.u = ((unsigned)(unsigned short)s) << 16;
  return a.f;
}

__device__ __forceinline__ void gl_lds16(const void* g, void* l) {
  __builtin_amdgcn_global_load_lds(
      (const __attribute__((address_space(1))) unsigned int*)g,
      (__attribute__((address_space(3))) unsigned int*)l, 16, 0, 0);
}

// ---- cast all four weight matrices f32 -> fp8 e4m3
__global__ __launch_bounds__(256) void cast_w(const float* __restrict__ wq, const float* __restrict__ wp,
                                              const float* __restrict__ w1, const float* __restrict__ w2,
                                              char* __restrict__ w8) {
  int i = blockIdx.x * 256 + threadIdx.x;
  int e = i << 2;
  const float* src; int off;
  if (e < 3145728)      { src = wq; off = e; }
  else if (e < 4194304) { src = wp; off = e - 3145728; }
  else if (e < 8388608) { src = w1; off = e - 4194304; }
  else                  { src = w2; off = e - 8388608; }
  float4 v = *reinterpret_cast<const float4*>(src + off);
  int pk = __builtin_amdgcn_cvt_pk_fp8_f32(v.x, v.y, 0, false);
  pk = __builtin_amdgcn_cvt_pk_fp8_f32(v.z, v.w, pk, true);
  *reinterpret_cast<int*>(w8 + e) = pk;
}

// ---- layernorm: f32 in -> fp8 e4m3 out; pad rows -> zeros
__global__ __launch_bounds__(256) void ln8_k(const float* __restrict__ x, const float* __restrict__ g,
                                             const float* __restrict__ bt, char* __restrict__ out, int mreal) {
  int row = blockIdx.x, t = threadIdx.x;
  char* orow = out + (size_t)row * C_;
  if (row >= mreal) {
    *reinterpret_cast<int*>(orow + (t << 2)) = 0;
    return;
  }
  float4 v = reinterpret_cast<const float4*>(x + (size_t)row * C_)[t];
  float s = v.x + v.y + v.z + v.w;
  float q = v.x*v.x + v.y*v.y + v.z*v.z + v.w*v.w;
#pragma unroll
  for (int m = 1; m < 64; m <<= 1) { s += __shfl_xor(s, m); q += __shfl_xor(q, m); }
  __shared__ float sb[8];
  int w = t >> 6;
  if ((t & 63) == 0) { sb[w] = s; sb[4 + w] = q; }
  __syncthreads();
  s = sb[0] + sb[1] + sb[2] + sb[3];
  q = sb[4] + sb[5] + sb[6] + sb[7];
  float mean = s * (1.f / C_);
  float rstd = rsqrtf(q * (1.f / C_) - mean * mean + 1e-5f);
  float4 gv = reinterpret_cast<const float4*>(g)[t];
  float4 bv = reinterpret_cast<const float4*>(bt)[t];
  float o0 = (v.x - mean) * rstd * gv.x + bv.x;
  float o1 = (v.y - mean) * rstd * gv.y + bv.y;
  float o2 = (v.z - mean) * rstd * gv.z + bv.z;
  float o3 = (v.w - mean) * rstd * gv.w + bv.w;
  int pk = __builtin_amdgcn_cvt_pk_fp8_f32(o0, o1, 0, false);
  pk = __builtin_amdgcn_cvt_pk_fp8_f32(o2, o3, pk, true);
  *reinterpret_cast<int*>(orow + (t << 2)) = pk;
}

// ---- layernorm: bf16 in -> fp8 e4m3 out; pad rows -> zeros
__global__ __launch_bounds__(256) void lnb8_k(const short* __restrict__ x, const float* __restrict__ g,
                                              const float* __restrict__ bt, char* __restrict__ out, int mreal) {
  int row = blockIdx.x, t = threadIdx.x;
  char* orow = out + (size_t)row * C_;
  if (row >= mreal) {
    *reinterpret_cast<int*>(orow + (t << 2)) = 0;
    return;
  }
  v4s v = reinterpret_cast<const v4s*>(x + (size_t)row * C_)[t];
  float f0 = bf2f(v[0]), f1 = bf2f(v[1]), f2 = bf2f(v[2]), f3 = bf2f(v[3]);
  float s = f0 + f1 + f2 + f3;
  float q = f0*f0 + f1*f1 + f2*f2 + f3*f3;
#pragma unroll
  for (int m = 1; m < 64; m <<= 1) { s += __shfl_xor(s, m); q += __shfl_xor(q, m); }
  __shared__ float sb[8];
  int w = t >> 6;
  if ((t & 63) == 0) { sb[w] = s; sb[4 + w] = q; }
  __syncthreads();
  s = sb[0] + sb[1] + sb[2] + sb[3];
  q = sb[4] + sb[5] + sb[6] + sb[7];
  float mean = s * (1.f / C_);
  float rstd = rsqrtf(q * (1.f / C_) - mean * mean + 1e-5f);
  float4 gv = reinterpret_cast<const float4*>(g)[t];
  float4 bv = reinterpret_cast<const float4*>(bt)[t];
  float o0 = (f0 - mean) * rstd * gv.x + bv.x;
  float o1 = (f1 - mean) * rstd * gv.y + bv.y;
  float o2 = (f2 - mean) * rstd * gv.z + bv.z;
  float o3 = (f3 - mean) * rstd * gv.w + bv.w;
  int pk = __builtin_amdgcn_cvt_pk_fp8_f32(o0, o1, 0, false);
  pk = __builtin_amdgcn_cvt_pk_fp8_f32(o2, o3, pk, true);
  *reinterpret_cast<int*>(orow + (t << 2)) = pk;
}

// ---- BM8x128-tile MX-fp8 GEMM (scales=1.0), 4-buffer single-barrier (R12-proven)
// 2-D XCD tiling: each XCD owns nTn/8 output columns (W-group 128-512KB, L2-resident)
// x ALL row-tiles, ordered tm-outer/tn-inner -> A streams once per XCD, no re-sweep.
// MODE8 0: QKV -> q8 fp8 (x0.125*log2e) | k8 fp8 | ov8 fp8 (V third, row-major)
// MODE8 1: ob16 = bf16( residf + gamma*(v+bias) )   (rows < mreal)   [proj]
// MODE8 2: o8 = e4m3( gelu_tanh(v+bias) )                            [fc1]
// MODE8 3: of32 = bf2f(residb) + gamma*(v+bias)   (rows < mreal)     [fc2]
template<int MODE8, int BM8>
__global__ __launch_bounds__(256) void gemm8_k(
    const char* __restrict__ A, const char* __restrict__ Bw,
    const float* __restrict__ bias, const float* __restrict__ residf,
    const short* __restrict__ residb,
    const float* __restrict__ gamma, char* __restrict__ o8,
    char* __restrict__ ov8, short* __restrict__ ob16,
    float* __restrict__ of32, char* __restrict__ ok8,
    int K, int Nc, int mreal, int nTn)
{
  constexpr int MF8 = BM8 / 64;
  __shared__ char As[4][BM8 * 64];
  __shared__ char Bs[4][128 * 64];
  int tid = threadIdx.x;
  int lane = tid & 63, wave = tid >> 6;
  int l31 = lane & 31, hi = lane >> 5;
  int sidx = blockIdx.x;
  int tpg = nTn >> 3;                         // tn columns per XCD (1, 3 or 4)
  int xcd = sidx & 7, local = sidx >> 3;      // nwg % 8 == 0 always
  int tn = xcd * tpg + local % tpg;           // W-group L2-resident per XCD
  int tm = local / tpg;                       // A row-tile streams once (tm-outer)
  int wr = wave >> 1, wc = wave & 1;

  v16f acc[MF8][2];
#pragma unroll
  for (int m = 0; m < MF8; m++)
#pragma unroll
    for (int n = 0; n < 2; n++)
#pragma unroll
      for (int r = 0; r < 16; r++) acc[m][n][r] = 0.f;

  int srow = wave * 16 + (lane >> 2);
  int sch = ((lane & 3) ^ ((srow >> 1) & 3)) << 4;
  const char* Ag = A + (size_t)(tm * BM8 + srow) * K + sch;
  const char* Bg = Bw + (size_t)(tn * 128 + srow) * K + sch;

#define STAGE8(bi, k0)                                                   \
  do {                                                                   \
    gl_lds16(Ag + (k0), &As[bi][wave * 1024]);                           \
    if constexpr (BM8 == 128)                                            \
      gl_lds16(Ag + (size_t)64 * K + (k0), &As[bi][4096 + wave * 1024]); \
    gl_lds16(Bg + (k0), &Bs[bi][wave * 1024]);                           \
    gl_lds16(Bg + (size_t)64 * K + (k0), &Bs[bi][4096 + wave * 1024]);   \
  } while (0)

  int kT = K >> 6;

  STAGE8(0, 0);
  STAGE8(1, 64);
  STAGE8(2, 128);

  int rowA = wr * (BM8 / 2) + l31;
  int rowB = wc * 64 + l31;
  int swA = (rowA >> 1) & 3, swB = (rowB >> 1) & 3;

  auto body = [&](int t, bool stage_next) {
    int bb = t & 3;
    __builtin_amdgcn_s_barrier();
    union { v4i q[2]; v8i v; } fa[MF8], fb[2];
#pragma unroll
    for (int m = 0; m < MF8; m++) {
      int row = rowA + m * 32;
      fa[m].q[0] = *reinterpret_cast<const v4i*>(&As[bb][row * 64 + (((2 * hi + 0) ^ swA) << 4)]);
      fa[m].q[1] = *reinterpret_cast<const v4i*>(&As[bb][row * 64 + (((2 * hi + 1) ^ swA) << 4)]);
    }
#pragma unroll
    for (int n = 0; n < 2; n++) {
      int row = rowB + n * 32;
      fb[n].q[0] = *reinterpret_cast<const v4i*>(&Bs[bb][row * 64 + (((2 * hi + 0) ^ swB) << 4)]);
      fb[n].q[1] = *reinterpret_cast<const v4i*>(&Bs[bb][row * 64 + (((2 * hi + 1) ^ swB) << 4)]);
    }
    if (stage_next) STAGE8((t + 3) & 3, (size_t)(t + 3) << 6);
    asm volatile("s_waitcnt lgkmcnt(0)" ::: "memory");
    __builtin_amdgcn_s_setprio(1);
#pragma unroll
    for (int m = 0; m < MF8; m++)
#pragma unroll
      for (int n = 0; n < 2; n++)
        acc[m][n] = __builtin_amdgcn_mfma_scale_f32_32x32x64_f8f6f4(
            fa[m].v, fb[n].v, acc[m][n], 0, 0, 0, 0x7f7f7f7f, 0, 0x7f7f7f7f);
    __builtin_amdgcn_s_setprio(0);
  };

  int t = 0;
  for (; t < kT - 2; ++t) {
    if constexpr (BM8 == 128) asm volatile("s_waitcnt vmcnt(8)" ::: "memory");
    else                      asm volatile("s_waitcnt vmcnt(6)" ::: "memory");
    body(t, t + 3 < kT);
  }
  if constexpr (BM8 == 128) asm volatile("s_waitcnt vmcnt(4)" ::: "memory");
  else                      asm volatile("s_waitcnt vmcnt(3)" ::: "memory");
  body(kT - 2, false);
  asm volatile("s_waitcnt vmcnt(0)" ::: "memory");
  body(kT - 1, false);
#undef STAGE8

#pragma unroll
  for (int m = 0; m < MF8; m++) {
#pragma unroll
    for (int n = 0; n < 2; n++) {
      int gc = tn * 128 + wc * 64 + n * 32 + l31;
      float bb = bias[gc];
      float gm = (MODE8 == 1 || MODE8 == 3) ? gamma[gc] : 0.f;
#pragma unroll
      for (int r = 0; r < 16; r++) {
        int crow = (r & 3) + 8 * (r >> 2) + 4 * hi;
        int gr = tm * BM8 + wr * (BM8 / 2) + m * 32 + crow;
        float v = acc[m][n][r] + bb;
        if (MODE8 == 0) {
          if (gc < 1024) {
            o8[(size_t)gr * 1024 + gc] = f2fp8(v * 0.18033688011112042f);   // Q * 0.125*log2e
          } else if (gc < 2048) {
            ok8[(size_t)gr * 1024 + gc - 1024] = f2fp8(v);                  // K
          } else {
            ov8[(size_t)gr * 1024 + gc - 2048] = f2fp8(v);                  // V (fp8, row-major)
          }
        } else if (MODE8 == 2) {
          float u2 = v * 1.5957691216f * (1.f + 0.044715f * v * v);
          float gl = v / (1.f + __expf(-u2));
          o8[(size_t)gr * Nc + gc] = f2fp8(gl);
        } else if (MODE8 == 1) {
          if (gr < mreal) ob16[(size_t)gr * Nc + gc] = f2bf(residf[(size_t)gr * Nc + gc] + gm * v);
        } else {
          if (gr < mreal) of32[(size_t)gr * Nc + gc] = bf2f(residb[(size_t)gr * Nc + gc]) + gm * v;
        }
      }
    }
  }
}

// ---- V repack: v8 fp8 [MPAD][1024] -> vt8[(bh*64+d)][NKV] fp8 (pure byte permute);
// per 64-col block: pos = cph*16+rr, cph = (hi16 ^ e) | ((blk ^ x)<<1), e=(d>>1)&1, x=(d>>2)&1
__global__ __launch_bounds__(256) void repack_v(const char* __restrict__ v8, char* __restrict__ vt8) {
  int kt = blockIdx.x;
  int bh = blockIdx.y;
  int b = bh >> 4, h = bh & 15;
  int t = threadIdx.x;
  __shared__ char T[128][72];   // row stride 72 (8B-aligned)
  int n0 = kt * 128;
  int r = t >> 1;
  int c0 = (t & 1) * 32;
  int tok = n0 + r;
  int tokc = tok < N_ ? tok : N_ - 1;
  const char* src = v8 + (size_t)(b * N_ + tokc) * 1024 + h * 64 + c0;
  union { v4i v; long l[2]; } a0, a1;
  a0.v = *reinterpret_cast<const v4i*>(src);
  a1.v = *reinterpret_cast<const v4i*>(src + 16);
  *reinterpret_cast<long*>(&T[r][c0])      = a0.l[0];
  *reinterpret_cast<long*>(&T[r][c0 + 8])  = a0.l[1];
  *reinterpret_cast<long*>(&T[r][c0 + 16]) = a1.l[0];
  *reinterpret_cast<long*>(&T[r][c0 + 24]) = a1.l[1];
  __syncthreads();
  int d = t & 63;
  int seg = t >> 6;
  int hb = seg >> 1;
  int q0 = (seg & 1) * 32;
  int ev = (d >> 1) & 1;
  int xv = (d >> 2) & 1;
  char buf[32];
#pragma unroll
  for (int j = 0; j < 32; j++) {
    int pos = q0 + j;
    int tok64 = ((((pos >> 5) & 1) ^ xv) << 5) |
                ((pos & 3) | ((((pos >> 4) & 1) ^ ev) << 2) | (((pos >> 2) & 3) << 3));
    buf[j] = T[hb * 64 + tok64][d];
  }
  char* dst = vt8 + ((size_t)(bh * 64 + d)) * NKV + n0 + hb * 64 + q0;
#pragma unroll
  for (int j = 0; j < 32; j += 16)
    *reinterpret_cast<v4i*>(dst + j) = *reinterpret_cast<const v4i*>(&buf[j]);
}

// ---- flash attention, all-fp8, KVBLK=128 phases, ls via ones-MFMA (R16-proven)
__global__ __launch_bounds__(256) void attn_k(const char* __restrict__ q8, const char* __restrict__ k8,
                                              const char* __restrict__ vt8, char* __restrict__ o8)
{
  int s = blockIdx.x + 11 * blockIdx.y;
  int ord = (s & 7) * 88 + (s >> 3);
  int qt = ord % 11, bh = ord / 11;
  int b = bh >> 4, h = bh & 15;
  int tid = threadIdx.x;
  int lane = tid & 63, wave = tid >> 6;
  int l31 = lane & 31, hi = lane >> 5;

  __shared__ char Ks[2][8192];   // [128 kv][64B], chunk ^= (kv>>1)&3
  __shared__ char Vs[2][8192];   // 2 blocks of [64 d][64B kv-cols], repack_v layout

  union F8 { v4i q[2]; v8i v; unsigned u[8]; };

  int qrow = qt * 128 + wave * 32 + l31;
  int qc = qrow < N_ ? qrow : N_ - 1;
  const char* qp = q8 + (size_t)(b * N_ + qc) * 1024 + h * 64 + hi * 32;
  F8 qf;
  qf.q[0] = *reinterpret_cast<const v4i*>(qp);
  qf.q[1] = *reinterpret_cast<const v4i*>(qp + 16);

  F8 ones;
#pragma unroll
  for (int w = 0; w < 8; w++) ones.u[w] = 0x38383838u;   // e4m3 1.0 x4

  v16f oa0, oa1, lsacc;
#pragma unroll
  for (int r = 0; r < 16; r++) { oa0[r] = 0.f; oa1[r] = 0.f; lsacc[r] = 0.f; }
  v16f vzero;
#pragma unroll
  for (int r = 0; r < 16; r++) vzero[r] = 0.f;

  int kvl = tid >> 2;
  int kc = (((tid & 3) ^ ((kvl >> 1) & 3)) << 4);
  const char* kpt = k8 + (size_t)(b * N_ + kvl) * 1024 + h * 64 + kc;
  const char* vpt = vt8 + ((size_t)(bh * 64) + kvl) * NKV + ((tid & 3) << 4);

  const int NT = NKV / 128;   // 11
#define STAGE_A(bi)                                              \
  do {                                                           \
    gl_lds16(kpt, &Ks[bi][wave * 1024]);                         \
    gl_lds16(kpt + (size_t)64 * 1024, &Ks[bi][4096 + wave * 1024]); \
    gl_lds16(vpt, &Vs[bi][wave * 1024]);                         \
    gl_lds16(vpt + 64, &Vs[bi][4096 + wave * 1024]);             \
    kpt += (size_t)128 * 1024; vpt += 128;                       \
  } while (0)

  STAGE_A(0);
  __syncthreads();
  int bi = 0;
  int k2 = (l31 >> 1) & 3;            // K chunk key (same for row+32)
  int ev = (l31 >> 1) & 1, xv = (l31 >> 2) & 1;   // V keys (same for d+32)
  int vc0 = ((hi ^ ev) | (xv << 1)) << 4;         // stored chunk for blk 0
  int vc1 = ((hi ^ ev) | ((1 ^ xv) << 1)) << 4;   // stored chunk for blk 1
  int kc0 = ((2 * hi) ^ k2) << 4;
  int kc1 = ((2 * hi + 1) ^ k2) << 4;

  for (int t = 0; t < NT; ++t) {
    if (t + 1 < NT) STAGE_A(bi ^ 1);

#pragma unroll
    for (int sub = 0; sub < 2; ++sub) {
      const char* Kb = &Ks[bi][sub * 4096];
      const char* Vb = &Vs[bi][sub * 4096];
      int kv0 = t * 128 + sub * 64;

      F8 ka, kb;
      ka.q[0] = *reinterpret_cast<const v4i*>(&Kb[l31 * 64 + kc0]);
      ka.q[1] = *reinterpret_cast<const v4i*>(&Kb[l31 * 64 + kc1]);
      kb.q[0] = *reinterpret_cast<const v4i*>(&Kb[(32 + l31) * 64 + kc0]);
      kb.q[1] = *reinterpret_cast<const v4i*>(&Kb[(32 + l31) * 64 + kc1]);
      v16f s0 = __builtin_amdgcn_mfma_scale_f32_32x32x64_f8f6f4(ka.v, qf.v, vzero, 0, 0, 0, 0x7f7f7f7f, 0, 0x7f7f7f7f);
      v16f s1 = __builtin_amdgcn_mfma_scale_f32_32x32x64_f8f6f4(kb.v, qf.v, vzero, 0, 0, 0, 0x7f7f7f7f, 0, 0x7f7f7f7f);

      if (kv0 + 64 > N_) {
#pragma unroll
        for (int r = 0; r < 16; r++) {
          int crow = (r & 3) + 8 * (r >> 2) + 4 * hi;
          if (kv0 + crow >= N_) s0[r] = -1e30f;
          if (kv0 + 32 + crow >= N_) s1[r] = -1e30f;
        }
      }

      float p0[16], p1[16];
#pragma unroll
      for (int r = 0; r < 16; r++) p0[r] = exp2f(s0[r]);
#pragma unroll
      for (int r = 0; r < 16; r++) p1[r] = exp2f(s1[r]);

      F8 pf;
#pragma unroll
      for (int w = 0; w < 4; w++) {
        int pk = __builtin_amdgcn_cvt_pk_fp8_f32(p0[4 * w], p0[4 * w + 1], 0, false);
        pf.u[w] = (unsigned)__builtin_amdgcn_cvt_pk_fp8_f32(p0[4 * w + 2], p0[4 * w + 3], pk, true);
      }
#pragma unroll
      for (int w = 0; w < 4; w++) {
        int pk = __builtin_amdgcn_cvt_pk_fp8_f32(p1[4 * w], p1[4 * w + 1], 0, false);
        pf.u[4 + w] = (unsigned)__builtin_amdgcn_cvt_pk_fp8_f32(p1[4 * w + 2], p1[4 * w + 3], pk, true);
      }

      // denominator from the same fp8 P (crow layout, no shuffles)
      lsacc = __builtin_amdgcn_mfma_scale_f32_32x32x64_f8f6f4(pf.v, ones.v, lsacc, 0, 0, 0, 0x7f7f7f7f, 0, 0x7f7f7f7f);

      F8 va, vb;
      va.q[0] = *reinterpret_cast<const v4i*>(&Vb[l31 * 64 + vc0]);
      va.q[1] = *reinterpret_cast<const v4i*>(&Vb[l31 * 64 + vc1]);
      vb.q[0] = *reinterpret_cast<const v4i*>(&Vb[(32 + l31) * 64 + vc0]);
      vb.q[1] = *reinterpret_cast<const v4i*>(&Vb[(32 + l31) * 64 + vc1]);
      oa0 = __builtin_amdgcn_mfma_scale_f32_32x32x64_f8f6f4(pf.v, va.v, oa0, 0, 0, 0, 0x7f7f7f7f, 0, 0x7f7f7f7f);
      oa1 = __builtin_amdgcn_mfma_scale_f32_32x32x64_f8f6f4(pf.v, vb.v, oa1, 0, 0, 0, 0x7f7f7f7f, 0, 0x7f7f7f7f);
    }

    __syncthreads();
    bi ^= 1;
  }
#undef STAGE_A

#pragma unroll
  for (int r = 0; r < 16; r++) {
    int crow = (r & 3) + 8 * (r >> 2) + 4 * hi;
    int qg = qt * 128 + wave * 32 + crow;
    if (qg < N_) {
      float iv = 1.f / lsacc[r];
      size_t base = (size_t)(b * N_ + qg) * 1024 + h * 64;
      o8[base + l31] = f2fp8(oa0[r] * iv);
      o8[base + 32 + l31] = f2fp8(oa1[r] * iv);
    }
  }
}

extern "C" void kernel_launch(void* const* d_in, const int* in_sizes, int n_in,
                              void* d_out, int out_size, void* d_ws, size_t ws_size,
                              hipStream_t stream) {
  const float* x     = (const float*)d_in[0];
  const float* ln1g  = (const float*)d_in[1];
  const float* ln1b  = (const float*)d_in[2];
  const float* wqkv  = (const float*)d_in[3];
  const float* bqkv  = (const float*)d_in[4];
  const float* wproj = (const float*)d_in[5];
  const float* bproj = (const float*)d_in[6];
  const float* g1    = (const float*)d_in[7];
  const float* ln2g  = (const float*)d_in[8];
  const float* ln2b  = (const float*)d_in[9];
  const float* wfc1  = (const float*)d_in[10];
  const float* bfc1  = (const float*)d_in[11];
  const float* wfc2  = (const float*)d_in[12];
  const float* bfc2  = (const float*)d_in[13];
  const float* g2    = (const float*)d_in[14];
  float* out = (float*)d_out;

  char* p = (char*)d_ws;
  char*  w8   = p;                            // fp8 weights: 12,582,912 B
  char*  h8   = p + 12582912;                 // fp8 [MPAD][1024] (LN1, later LN2)
  char*  q8   = p + 18219008;                 // fp8 [5632][1024]
  char*  k8   = p + 23986176;                 // fp8 [5632][1024] (slack rows for OOB staging)
  char*  v8   = p + 29753344;                 // fp8 [MPAD][1024] (V third, row-major)
  char*  vt8  = p + 41025536;                 // fp8 [64*64][NKV] V^T, permuted
  char*  ob8  = p + 46792704;                 // fp8 [MPAD][1024] (attn out)
  short* x2b  = (short*)(p + 52428800);       // bf16 [MPAD][1024] residual stream
  char*  mlp8 = p + 74973184;                 // fp8 [MPAD][4096] (end 97,517,568)

  cast_w<<<12288, 256, 0, stream>>>(wqkv, wproj, wfc1, wfc2, w8);
  ln8_k<<<MPAD, 256, 0, stream>>>(x, ln1g, ln1b, h8, M_);
  gemm8_k<0, 128><<<1032, 256, 0, stream>>>(h8, w8, bqkv, nullptr, nullptr, nullptr,
                                            q8, v8, nullptr, nullptr, k8, 1024, 3072, M_, 24);
  repack_v<<<dim3(11, 64), 256, 0, stream>>>(v8, vt8);
  attn_k<<<dim3(11, 64), 256, 0, stream>>>(q8, k8, vt8, ob8);
  gemm8_k<1, 64><<<688, 256, 0, stream>>>(ob8, w8 + 3145728, bproj, x, nullptr, g1,
                                          nullptr, nullptr, x2b, nullptr, nullptr, 1024, 1024, M_, 8);
  lnb8_k<<<MPAD, 256, 0, stream>>>(x2b, ln2g, ln2b, h8, M_);
  gemm8_k<2, 128><<<1376, 256, 0, stream>>>(h8, w8 + 4194304, bfc1, nullptr, nullptr, nullptr,
                                            mlp8, nullptr, nullptr, nullptr, nullptr, 1024, 4096, M_, 32);
  gemm8_k<3, 64><<<688, 256, 0, stream>>>(mlp8, w8 + 8388608, bfc2, nullptr, x2b, g2,
                                          nullptr, nullptr, nullptr, out, nullptr, 4096, 1024, M_, 8);
}

// Round 23
// 216.320 us; speedup vs baseline: 1.0659x; 1.0659x over previous
//
#include <hip/hip_runtime.h>
#include <hip/hip_bf16.h>
#include <math.h>

#define B_ 4
#define N_ 1370
#define C_ 1024
#define H_ 16
#define DH_ 64
#define HID_ 4096
#define M_ (B_*N_)      // 5480
#define MPAD 5504       // 43*128 = 86*64
#define NKV 1408        // 11*128 padded kv

typedef short v4s __attribute__((ext_vector_type(4)));
typedef float v16f __attribute__((ext_vector_type(16)));
typedef int v4i __attribute__((ext_vector_type(4)));
typedef int v8i __attribute__((ext_vector_type(8)));

__device__ __forceinline__ char f2fp8(float x) {
  int pk = __builtin_amdgcn_cvt_pk_fp8_f32(x, x, 0, false);
  return (char)(pk & 0xff);
}
__device__ __forceinline__ short f2bf(float x) {
  union { float f; unsigned u; } a; a.f = x;
  unsigned r = (a.u + 0x7fffu + ((a.u >> 16) & 1u)) >> 16;
  return (short)r;
}
__device__ __forceinline__ float bf2f(short s) {
  union { unsigned u; float f; } a; a.u = ((unsigned)(unsigned short)s) << 16;
  return a.f;
}

__device__ __forceinline__ void gl_lds16(const void* g, void* l) {
  __builtin_amdgcn_global_load_lds(
      (const __attribute__((address_space(1))) unsigned int*)g,
      (__attribute__((address_space(3))) unsigned int*)l, 16, 0, 0);
}

// ---- cast all four weight matrices f32 -> fp8 e4m3
__global__ __launch_bounds__(256) void cast_w(const float* __restrict__ wq, const float* __restrict__ wp,
                                              const float* __restrict__ w1, const float* __restrict__ w2,
                                              char* __restrict__ w8) {
  int i = blockIdx.x * 256 + threadIdx.x;
  int e = i << 2;
  const float* src; int off;
  if (e < 3145728)      { src = wq; off = e; }
  else if (e < 4194304) { src = wp; off = e - 3145728; }
  else if (e < 8388608) { src = w1; off = e - 4194304; }
  else                  { src = w2; off = e - 8388608; }
  float4 v = *reinterpret_cast<const float4*>(src + off);
  int pk = __builtin_amdgcn_cvt_pk_fp8_f32(v.x, v.y, 0, false);
  pk = __builtin_amdgcn_cvt_pk_fp8_f32(v.z, v.w, pk, true);
  *reinterpret_cast<int*>(w8 + e) = pk;
}

// ---- layernorm: f32 in -> fp8 e4m3 out; pad rows -> zeros
__global__ __launch_bounds__(256) void ln8_k(const float* __restrict__ x, const float* __restrict__ g,
                                             const float* __restrict__ bt, char* __restrict__ out, int mreal) {
  int row = blockIdx.x, t = threadIdx.x;
  char* orow = out + (size_t)row * C_;
  if (row >= mreal) {
    *reinterpret_cast<int*>(orow + (t << 2)) = 0;
    return;
  }
  float4 v = reinterpret_cast<const float4*>(x + (size_t)row * C_)[t];
  float s = v.x + v.y + v.z + v.w;
  float q = v.x*v.x + v.y*v.y + v.z*v.z + v.w*v.w;
#pragma unroll
  for (int m = 1; m < 64; m <<= 1) { s += __shfl_xor(s, m); q += __shfl_xor(q, m); }
  __shared__ float sb[8];
  int w = t >> 6;
  if ((t & 63) == 0) { sb[w] = s; sb[4 + w] = q; }
  __syncthreads();
  s = sb[0] + sb[1] + sb[2] + sb[3];
  q = sb[4] + sb[5] + sb[6] + sb[7];
  float mean = s * (1.f / C_);
  float rstd = rsqrtf(q * (1.f / C_) - mean * mean + 1e-5f);
  float4 gv = reinterpret_cast<const float4*>(g)[t];
  float4 bv = reinterpret_cast<const float4*>(bt)[t];
  float o0 = (v.x - mean) * rstd * gv.x + bv.x;
  float o1 = (v.y - mean) * rstd * gv.y + bv.y;
  float o2 = (v.z - mean) * rstd * gv.z + bv.z;
  float o3 = (v.w - mean) * rstd * gv.w + bv.w;
  int pk = __builtin_amdgcn_cvt_pk_fp8_f32(o0, o1, 0, false);
  pk = __builtin_amdgcn_cvt_pk_fp8_f32(o2, o3, pk, true);
  *reinterpret_cast<int*>(orow + (t << 2)) = pk;
}

// ---- layernorm: bf16 in -> fp8 e4m3 out; pad rows -> zeros
__global__ __launch_bounds__(256) void lnb8_k(const short* __restrict__ x, const float* __restrict__ g,
                                              const float* __restrict__ bt, char* __restrict__ out, int mreal) {
  int row = blockIdx.x, t = threadIdx.x;
  char* orow = out + (size_t)row * C_;
  if (row >= mreal) {
    *reinterpret_cast<int*>(orow + (t << 2)) = 0;
    return;
  }
  v4s v = reinterpret_cast<const v4s*>(x + (size_t)row * C_)[t];
  float f0 = bf2f(v[0]), f1 = bf2f(v[1]), f2 = bf2f(v[2]), f3 = bf2f(v[3]);
  float s = f0 + f1 + f2 + f3;
  float q = f0*f0 + f1*f1 + f2*f2 + f3*f3;
#pragma unroll
  for (int m = 1; m < 64; m <<= 1) { s += __shfl_xor(s, m); q += __shfl_xor(q, m); }
  __shared__ float sb[8];
  int w = t >> 6;
  if ((t & 63) == 0) { sb[w] = s; sb[4 + w] = q; }
  __syncthreads();
  s = sb[0] + sb[1] + sb[2] + sb[3];
  q = sb[4] + sb[5] + sb[6] + sb[7];
  float mean = s * (1.f / C_);
  float rstd = rsqrtf(q * (1.f / C_) - mean * mean + 1e-5f);
  float4 gv = reinterpret_cast<const float4*>(g)[t];
  float4 bv = reinterpret_cast<const float4*>(bt)[t];
  float o0 = (f0 - mean) * rstd * gv.x + bv.x;
  float o1 = (f1 - mean) * rstd * gv.y + bv.y;
  float o2 = (f2 - mean) * rstd * gv.z + bv.z;
  float o3 = (f3 - mean) * rstd * gv.w + bv.w;
  int pk = __builtin_amdgcn_cvt_pk_fp8_f32(o0, o1, 0, false);
  pk = __builtin_amdgcn_cvt_pk_fp8_f32(o2, o3, pk, true);
  *reinterpret_cast<int*>(orow + (t << 2)) = pk;
}

// ---- BM8x128-tile MX-fp8 GEMM (scales=1.0), 4-buffer single-barrier (R12-proven)
// M-major XCD-chunked mapping: each XCD owns an L2-resident A slice, streams W
// MODE8 0: QKV -> q8 fp8 (x0.125*log2e) | k8 fp8 | ov8 fp8 (V third, row-major)
// MODE8 1: ob16 = bf16( residf + gamma*(v+bias) )   (rows < mreal)   [proj]
// MODE8 2: o8 = e4m3( gelu_tanh(v+bias) )                            [fc1]
// MODE8 3: of32 = bf2f(residb) + gamma*(v+bias)   (rows < mreal)     [fc2]
template<int MODE8, int BM8>
__global__ __launch_bounds__(256) void gemm8_k(
    const char* __restrict__ A, const char* __restrict__ Bw,
    const float* __restrict__ bias, const float* __restrict__ residf,
    const short* __restrict__ residb,
    const float* __restrict__ gamma, char* __restrict__ o8,
    char* __restrict__ ov8, short* __restrict__ ob16,
    float* __restrict__ of32, char* __restrict__ ok8,
    int K, int Nc, int mreal, int nTn)
{
  constexpr int MF8 = BM8 / 64;
  __shared__ char As[4][BM8 * 64];
  __shared__ char Bs[4][128 * 64];
  int tid = threadIdx.x;
  int lane = tid & 63, wave = tid >> 6;
  int l31 = lane & 31, hi = lane >> 5;
  int nwg = gridDim.x;
  int sidx = blockIdx.x;
  int ord = (sidx & 7) * (nwg >> 3) + (sidx >> 3);   // XCD-chunked (nwg % 8 == 0)
  int tm = ord / nTn, tn = ord % nTn;                 // M-major: A slice L2-resident
  int wr = wave >> 1, wc = wave & 1;

  v16f acc[MF8][2];
#pragma unroll
  for (int m = 0; m < MF8; m++)
#pragma unroll
    for (int n = 0; n < 2; n++)
#pragma unroll
      for (int r = 0; r < 16; r++) acc[m][n][r] = 0.f;

  int srow = wave * 16 + (lane >> 2);
  int sch = ((lane & 3) ^ ((srow >> 1) & 3)) << 4;
  const char* Ag = A + (size_t)(tm * BM8 + srow) * K + sch;
  const char* Bg = Bw + (size_t)(tn * 128 + srow) * K + sch;

#define STAGE8(bi, k0)                                                   \
  do {                                                                   \
    gl_lds16(Ag + (k0), &As[bi][wave * 1024]);                           \
    if constexpr (BM8 == 128)                                            \
      gl_lds16(Ag + (size_t)64 * K + (k0), &As[bi][4096 + wave * 1024]); \
    gl_lds16(Bg + (k0), &Bs[bi][wave * 1024]);                           \
    gl_lds16(Bg + (size_t)64 * K + (k0), &Bs[bi][4096 + wave * 1024]);   \
  } while (0)

  int kT = K >> 6;

  STAGE8(0, 0);
  STAGE8(1, 64);
  STAGE8(2, 128);

  int rowA = wr * (BM8 / 2) + l31;
  int rowB = wc * 64 + l31;
  int swA = (rowA >> 1) & 3, swB = (rowB >> 1) & 3;

  auto body = [&](int t, bool stage_next) {
    int bb = t & 3;
    __builtin_amdgcn_s_barrier();
    union { v4i q[2]; v8i v; } fa[MF8], fb[2];
#pragma unroll
    for (int m = 0; m < MF8; m++) {
      int row = rowA + m * 32;
      fa[m].q[0] = *reinterpret_cast<const v4i*>(&As[bb][row * 64 + (((2 * hi + 0) ^ swA) << 4)]);
      fa[m].q[1] = *reinterpret_cast<const v4i*>(&As[bb][row * 64 + (((2 * hi + 1) ^ swA) << 4)]);
    }
#pragma unroll
    for (int n = 0; n < 2; n++) {
      int row = rowB + n * 32;
      fb[n].q[0] = *reinterpret_cast<const v4i*>(&Bs[bb][row * 64 + (((2 * hi + 0) ^ swB) << 4)]);
      fb[n].q[1] = *reinterpret_cast<const v4i*>(&Bs[bb][row * 64 + (((2 * hi + 1) ^ swB) << 4)]);
    }
    if (stage_next) STAGE8((t + 3) & 3, (size_t)(t + 3) << 6);
    asm volatile("s_waitcnt lgkmcnt(0)" ::: "memory");
    __builtin_amdgcn_s_setprio(1);
#pragma unroll
    for (int m = 0; m < MF8; m++)
#pragma unroll
      for (int n = 0; n < 2; n++)
        acc[m][n] = __builtin_amdgcn_mfma_scale_f32_32x32x64_f8f6f4(
            fa[m].v, fb[n].v, acc[m][n], 0, 0, 0, 0x7f7f7f7f, 0, 0x7f7f7f7f);
    __builtin_amdgcn_s_setprio(0);
  };

  int t = 0;
  for (; t < kT - 2; ++t) {
    if constexpr (BM8 == 128) asm volatile("s_waitcnt vmcnt(8)" ::: "memory");
    else                      asm volatile("s_waitcnt vmcnt(6)" ::: "memory");
    body(t, t + 3 < kT);
  }
  if constexpr (BM8 == 128) asm volatile("s_waitcnt vmcnt(4)" ::: "memory");
  else                      asm volatile("s_waitcnt vmcnt(3)" ::: "memory");
  body(kT - 2, false);
  asm volatile("s_waitcnt vmcnt(0)" ::: "memory");
  body(kT - 1, false);
#undef STAGE8

#pragma unroll
  for (int m = 0; m < MF8; m++) {
#pragma unroll
    for (int n = 0; n < 2; n++) {
      int gc = tn * 128 + wc * 64 + n * 32 + l31;
      float bb = bias[gc];
      float gm = (MODE8 == 1 || MODE8 == 3) ? gamma[gc] : 0.f;
#pragma unroll
      for (int r = 0; r < 16; r++) {
        int crow = (r & 3) + 8 * (r >> 2) + 4 * hi;
        int gr = tm * BM8 + wr * (BM8 / 2) + m * 32 + crow;
        float v = acc[m][n][r] + bb;
        if (MODE8 == 0) {
          if (gc < 1024) {
            o8[(size_t)gr * 1024 + gc] = f2fp8(v * 0.18033688011112042f);   // Q * 0.125*log2e
          } else if (gc < 2048) {
            ok8[(size_t)gr * 1024 + gc - 1024] = f2fp8(v);                  // K
          } else {
            ov8[(size_t)gr * 1024 + gc - 2048] = f2fp8(v);                  // V (fp8, row-major)
          }
        } else if (MODE8 == 2) {
          float u2 = v * 1.5957691216f * (1.f + 0.044715f * v * v);
          float gl = v / (1.f + __expf(-u2));
          o8[(size_t)gr * Nc + gc] = f2fp8(gl);
        } else if (MODE8 == 1) {
          if (gr < mreal) ob16[(size_t)gr * Nc + gc] = f2bf(residf[(size_t)gr * Nc + gc] + gm * v);
        } else {
          if (gr < mreal) of32[(size_t)gr * Nc + gc] = bf2f(residb[(size_t)gr * Nc + gc]) + gm * v;
        }
      }
    }
  }
}

// ---- V repack: v8 fp8 [MPAD][1024] -> vt8[(bh*64+d)][NKV] fp8 (pure byte permute);
// per 64-col block: pos = cph*16+rr, cph = (hi16 ^ e) | ((blk ^ x)<<1), e=(d>>1)&1, x=(d>>2)&1
__global__ __launch_bounds__(256) void repack_v(const char* __restrict__ v8, char* __restrict__ vt8) {
  int kt = blockIdx.x;
  int bh = blockIdx.y;
  int b = bh >> 4, h = bh & 15;
  int t = threadIdx.x;
  __shared__ char T[128][72];   // row stride 72 (8B-aligned)
  int n0 = kt * 128;
  int r = t >> 1;
  int c0 = (t & 1) * 32;
  int tok = n0 + r;
  int tokc = tok < N_ ? tok : N_ - 1;
  const char* src = v8 + (size_t)(b * N_ + tokc) * 1024 + h * 64 + c0;
  union { v4i v; long l[2]; } a0, a1;
  a0.v = *reinterpret_cast<const v4i*>(src);
  a1.v = *reinterpret_cast<const v4i*>(src + 16);
  *reinterpret_cast<long*>(&T[r][c0])      = a0.l[0];
  *reinterpret_cast<long*>(&T[r][c0 + 8])  = a0.l[1];
  *reinterpret_cast<long*>(&T[r][c0 + 16]) = a1.l[0];
  *reinterpret_cast<long*>(&T[r][c0 + 24]) = a1.l[1];
  __syncthreads();
  int d = t & 63;
  int seg = t >> 6;
  int hb = seg >> 1;
  int q0 = (seg & 1) * 32;
  int ev = (d >> 1) & 1;
  int xv = (d >> 2) & 1;
  char buf[32];
#pragma unroll
  for (int j = 0; j < 32; j++) {
    int pos = q0 + j;
    int tok64 = ((((pos >> 5) & 1) ^ xv) << 5) |
                ((pos & 3) | ((((pos >> 4) & 1) ^ ev) << 2) | (((pos >> 2) & 3) << 3));
    buf[j] = T[hb * 64 + tok64][d];
  }
  char* dst = vt8 + ((size_t)(bh * 64 + d)) * NKV + n0 + hb * 64 + q0;
#pragma unroll
  for (int j = 0; j < 32; j += 16)
    *reinterpret_cast<v4i*>(dst + j) = *reinterpret_cast<const v4i*>(&buf[j]);
}

// ---- flash attention, all-fp8, KVBLK=128 phases, ls via ones-MFMA (R16-proven)
__global__ __launch_bounds__(256) void attn_k(const char* __restrict__ q8, const char* __restrict__ k8,
                                              const char* __restrict__ vt8, char* __restrict__ o8)
{
  int s = blockIdx.x + 11 * blockIdx.y;
  int ord = (s & 7) * 88 + (s >> 3);
  int qt = ord % 11, bh = ord / 11;
  int b = bh >> 4, h = bh & 15;
  int tid = threadIdx.x;
  int lane = tid & 63, wave = tid >> 6;
  int l31 = lane & 31, hi = lane >> 5;

  __shared__ char Ks[2][8192];   // [128 kv][64B], chunk ^= (kv>>1)&3
  __shared__ char Vs[2][8192];   // 2 blocks of [64 d][64B kv-cols], repack_v layout

  union F8 { v4i q[2]; v8i v; unsigned u[8]; };

  int qrow = qt * 128 + wave * 32 + l31;
  int qc = qrow < N_ ? qrow : N_ - 1;
  const char* qp = q8 + (size_t)(b * N_ + qc) * 1024 + h * 64 + hi * 32;
  F8 qf;
  qf.q[0] = *reinterpret_cast<const v4i*>(qp);
  qf.q[1] = *reinterpret_cast<const v4i*>(qp + 16);

  F8 ones;
#pragma unroll
  for (int w = 0; w < 8; w++) ones.u[w] = 0x38383838u;   // e4m3 1.0 x4

  v16f oa0, oa1, lsacc;
#pragma unroll
  for (int r = 0; r < 16; r++) { oa0[r] = 0.f; oa1[r] = 0.f; lsacc[r] = 0.f; }
  v16f vzero;
#pragma unroll
  for (int r = 0; r < 16; r++) vzero[r] = 0.f;

  int kvl = tid >> 2;
  int kc = (((tid & 3) ^ ((kvl >> 1) & 3)) << 4);
  const char* kpt = k8 + (size_t)(b * N_ + kvl) * 1024 + h * 64 + kc;
  const char* vpt = vt8 + ((size_t)(bh * 64) + kvl) * NKV + ((tid & 3) << 4);

  const int NT = NKV / 128;   // 11
#define STAGE_A(bi)                                              \
  do {                                                           \
    gl_lds16(kpt, &Ks[bi][wave * 1024]);                         \
    gl_lds16(kpt + (size_t)64 * 1024, &Ks[bi][4096 + wave * 1024]); \
    gl_lds16(vpt, &Vs[bi][wave * 1024]);                         \
    gl_lds16(vpt + 64, &Vs[bi][4096 + wave * 1024]);             \
    kpt += (size_t)128 * 1024; vpt += 128;                       \
  } while (0)

  STAGE_A(0);
  __syncthreads();
  int bi = 0;
  int k2 = (l31 >> 1) & 3;            // K chunk key (same for row+32)
  int ev = (l31 >> 1) & 1, xv = (l31 >> 2) & 1;   // V keys (same for d+32)
  int vc0 = ((hi ^ ev) | (xv << 1)) << 4;         // stored chunk for blk 0
  int vc1 = ((hi ^ ev) | ((1 ^ xv) << 1)) << 4;   // stored chunk for blk 1
  int kc0 = ((2 * hi) ^ k2) << 4;
  int kc1 = ((2 * hi + 1) ^ k2) << 4;

  for (int t = 0; t < NT; ++t) {
    if (t + 1 < NT) STAGE_A(bi ^ 1);

#pragma unroll
    for (int sub = 0; sub < 2; ++sub) {
      const char* Kb = &Ks[bi][sub * 4096];
      const char* Vb = &Vs[bi][sub * 4096];
      int kv0 = t * 128 + sub * 64;

      F8 ka, kb;
      ka.q[0] = *reinterpret_cast<const v4i*>(&Kb[l31 * 64 + kc0]);
      ka.q[1] = *reinterpret_cast<const v4i*>(&Kb[l31 * 64 + kc1]);
      kb.q[0] = *reinterpret_cast<const v4i*>(&Kb[(32 + l31) * 64 + kc0]);
      kb.q[1] = *reinterpret_cast<const v4i*>(&Kb[(32 + l31) * 64 + kc1]);
      v16f s0 = __builtin_amdgcn_mfma_scale_f32_32x32x64_f8f6f4(ka.v, qf.v, vzero, 0, 0, 0, 0x7f7f7f7f, 0, 0x7f7f7f7f);
      v16f s1 = __builtin_amdgcn_mfma_scale_f32_32x32x64_f8f6f4(kb.v, qf.v, vzero, 0, 0, 0, 0x7f7f7f7f, 0, 0x7f7f7f7f);

      if (kv0 + 64 > N_) {
#pragma unroll
        for (int r = 0; r < 16; r++) {
          int crow = (r & 3) + 8 * (r >> 2) + 4 * hi;
          if (kv0 + crow >= N_) s0[r] = -1e30f;
          if (kv0 + 32 + crow >= N_) s1[r] = -1e30f;
        }
      }

      float p0[16], p1[16];
#pragma unroll
      for (int r = 0; r < 16; r++) p0[r] = exp2f(s0[r]);
#pragma unroll
      for (int r = 0; r < 16; r++) p1[r] = exp2f(s1[r]);

      F8 pf;
#pragma unroll
      for (int w = 0; w < 4; w++) {
        int pk = __builtin_amdgcn_cvt_pk_fp8_f32(p0[4 * w], p0[4 * w + 1], 0, false);
        pf.u[w] = (unsigned)__builtin_amdgcn_cvt_pk_fp8_f32(p0[4 * w + 2], p0[4 * w + 3], pk, true);
      }
#pragma unroll
      for (int w = 0; w < 4; w++) {
        int pk = __builtin_amdgcn_cvt_pk_fp8_f32(p1[4 * w], p1[4 * w + 1], 0, false);
        pf.u[4 + w] = (unsigned)__builtin_amdgcn_cvt_pk_fp8_f32(p1[4 * w + 2], p1[4 * w + 3], pk, true);
      }

      // denominator from the same fp8 P (crow layout, no shuffles)
      lsacc = __builtin_amdgcn_mfma_scale_f32_32x32x64_f8f6f4(pf.v, ones.v, lsacc, 0, 0, 0, 0x7f7f7f7f, 0, 0x7f7f7f7f);

      F8 va, vb;
      va.q[0] = *reinterpret_cast<const v4i*>(&Vb[l31 * 64 + vc0]);
      va.q[1] = *reinterpret_cast<const v4i*>(&Vb[l31 * 64 + vc1]);
      vb.q[0] = *reinterpret_cast<const v4i*>(&Vb[(32 + l31) * 64 + vc0]);
      vb.q[1] = *reinterpret_cast<const v4i*>(&Vb[(32 + l31) * 64 + vc1]);
      oa0 = __builtin_amdgcn_mfma_scale_f32_32x32x64_f8f6f4(pf.v, va.v, oa0, 0, 0, 0, 0x7f7f7f7f, 0, 0x7f7f7f7f);
      oa1 = __builtin_amdgcn_mfma_scale_f32_32x32x64_f8f6f4(pf.v, vb.v, oa1, 0, 0, 0, 0x7f7f7f7f, 0, 0x7f7f7f7f);
    }

    __syncthreads();
    bi ^= 1;
  }
#undef STAGE_A

#pragma unroll
  for (int r = 0; r < 16; r++) {
    int crow = (r & 3) + 8 * (r >> 2) + 4 * hi;
    int qg = qt * 128 + wave * 32 + crow;
    if (qg < N_) {
      float iv = 1.f / lsacc[r];
      size_t base = (size_t)(b * N_ + qg) * 1024 + h * 64;
      o8[base + l31] = f2fp8(oa0[r] * iv);
      o8[base + 32 + l31] = f2fp8(oa1[r] * iv);
    }
  }
}

extern "C" void kernel_launch(void* const* d_in, const int* in_sizes, int n_in,
                              void* d_out, int out_size, void* d_ws, size_t ws_size,
                              hipStream_t stream) {
  const float* x     = (const float*)d_in[0];
  const float* ln1g  = (const float*)d_in[1];
  const float* ln1b  = (const float*)d_in[2];
  const float* wqkv  = (const float*)d_in[3];
  const float* bqkv  = (const float*)d_in[4];
  const float* wproj = (const float*)d_in[5];
  const float* bproj = (const float*)d_in[6];
  const float* g1    = (const float*)d_in[7];
  const float* ln2g  = (const float*)d_in[8];
  const float* ln2b  = (const float*)d_in[9];
  const float* wfc1  = (const float*)d_in[10];
  const float* bfc1  = (const float*)d_in[11];
  const float* wfc2  = (const float*)d_in[12];
  const float* bfc2  = (const float*)d_in[13];
  const float* g2    = (const float*)d_in[14];
  float* out = (float*)d_out;

  char* p = (char*)d_ws;
  char*  w8   = p;                            // fp8 weights: 12,582,912 B
  char*  h8   = p + 12582912;                 // fp8 [MPAD][1024] (LN1, later LN2)
  char*  q8   = p + 18219008;                 // fp8 [5632][1024]
  char*  k8   = p + 23986176;                 // fp8 [5632][1024] (slack rows for OOB staging)
  char*  v8   = p + 29753344;                 // fp8 [MPAD][1024] (V third, row-major)
  char*  vt8  = p + 41025536;                 // fp8 [64*64][NKV] V^T, permuted
  char*  ob8  = p + 46792704;                 // fp8 [MPAD][1024] (attn out)
  short* x2b  = (short*)(p + 52428800);       // bf16 [MPAD][1024] residual stream
  char*  mlp8 = p + 74973184;                 // fp8 [MPAD][4096] (end 97,517,568)

  cast_w<<<12288, 256, 0, stream>>>(wqkv, wproj, wfc1, wfc2, w8);
  ln8_k<<<MPAD, 256, 0, stream>>>(x, ln1g, ln1b, h8, M_);
  gemm8_k<0, 128><<<1032, 256, 0, stream>>>(h8, w8, bqkv, nullptr, nullptr, nullptr,
                                            q8, v8, nullptr, nullptr, k8, 1024, 3072, M_, 24);
  repack_v<<<dim3(11, 64), 256, 0, stream>>>(v8, vt8);
  attn_k<<<dim3(11, 64), 256, 0, stream>>>(q8, k8, vt8, ob8);
  gemm8_k<1, 64><<<688, 256, 0, stream>>>(ob8, w8 + 3145728, bproj, x, nullptr, g1,
                                          nullptr, nullptr, x2b, nullptr, nullptr, 1024, 1024, M_, 8);
  lnb8_k<<<MPAD, 256, 0, stream>>>(x2b, ln2g, ln2b, h8, M_);
  gemm8_k<2, 128><<<1376, 256, 0, stream>>>(h8, w8 + 4194304, bfc1, nullptr, nullptr, nullptr,
                                            mlp8, nullptr, nullptr, nullptr, nullptr, 1024, 4096, M_, 32);
  gemm8_k<3, 64><<<688, 256, 0, stream>>>(mlp8, w8 + 8388608, bfc2, nullptr, x2b, g2,
                                          nullptr, nullptr, nullptr, out, nullptr, 4096, 1024, M_, 8);
}